// Round 1
// baseline (64.491 us; speedup 1.0000x reference)
//
#include <hip/hip_runtime.h>

#define HH 1024
#define VV 32000
#define SS 2048

__device__ __forceinline__ float wave_sum64(float v) {
    #pragma unroll
    for (int off = 32; off; off >>= 1) v += __shfl_down(v, off, 64);
    return v;
}

// ---------------- Kernel A: scores[s] = dot(E[s,:], h0) ----------------
// one wave per row; 512 blocks x 256 threads = 2048 waves
__global__ __launch_bounds__(256) void scores_kernel(
    const float* __restrict__ E, const float* __restrict__ h,
    float* __restrict__ scores) {
    int wave = (blockIdx.x * blockDim.x + threadIdx.x) >> 6;
    int lane = threadIdx.x & 63;
    const float4* Er = (const float4*)(E + (size_t)wave * HH);
    const float4* hv = (const float4*)h;
    float acc = 0.f;
    #pragma unroll
    for (int k = 0; k < 4; ++k) {
        float4 e = Er[lane + 64 * k];
        float4 x = hv[lane + 64 * k];
        acc += e.x * x.x + e.y * x.y + e.z * x.z + e.w * x.w;
    }
    acc = wave_sum64(acc);
    if (lane == 0) scores[wave] = acc;
}

// ---------------- Kernel B: softmax(scores) -> attn (ws + out), zero ctx ----------------
// single block of 1024 threads, 2 elements each
__global__ __launch_bounds__(1024) void softmax_kernel(
    const float* __restrict__ scores,
    float* __restrict__ attn_ws, float* __restrict__ attn_out,
    float* __restrict__ ctx_acc) {
    __shared__ float red[16];
    __shared__ float s_max, s_sum;
    int t = threadIdx.x;
    float s0 = scores[t], s1 = scores[t + 1024];
    float m = fmaxf(s0, s1);
    #pragma unroll
    for (int off = 32; off; off >>= 1) m = fmaxf(m, __shfl_xor(m, off, 64));
    if ((t & 63) == 0) red[t >> 6] = m;
    __syncthreads();
    if (t == 0) {
        float v = red[0];
        #pragma unroll
        for (int i = 1; i < 16; ++i) v = fmaxf(v, red[i]);
        s_max = v;
    }
    __syncthreads();
    float e0 = expf(s0 - s_max), e1 = expf(s1 - s_max);
    float sum = e0 + e1;
    sum = wave_sum64(sum);
    if ((t & 63) == 0) red[t >> 6] = sum;
    __syncthreads();
    if (t == 0) {
        float v = 0.f;
        #pragma unroll
        for (int i = 0; i < 16; ++i) v += red[i];
        s_sum = v;
    }
    __syncthreads();
    float inv = 1.f / s_sum;
    float a0 = e0 * inv, a1 = e1 * inv;
    attn_ws[t] = a0;  attn_ws[t + 1024] = a1;
    attn_out[t] = a0; attn_out[t + 1024] = a1;
    ctx_acc[t] = 0.f;   // zero the ctx accumulator (1024 floats)
}

// ---------------- Kernel C: ctx[:] += sum_s attn[s] * E[s,:] ----------------
// 128 blocks x 256 threads; block handles 16 rows; thread owns 4 consecutive cols
__global__ __launch_bounds__(256) void ctx_kernel(
    const float* __restrict__ E, const float* __restrict__ attn,
    float* __restrict__ ctx_acc) {
    int t = threadIdx.x;
    int rowBase = blockIdx.x * 16;
    float4 acc = make_float4(0.f, 0.f, 0.f, 0.f);
    #pragma unroll
    for (int s = 0; s < 16; ++s) {
        float w = attn[rowBase + s];
        float4 e = ((const float4*)(E + (size_t)(rowBase + s) * HH))[t];
        acc.x += w * e.x; acc.y += w * e.y; acc.z += w * e.z; acc.w += w * e.w;
    }
    atomicAdd(&ctx_acc[4 * t + 0], acc.x);
    atomicAdd(&ctx_acc[4 * t + 1], acc.y);
    atomicAdd(&ctx_acc[4 * t + 2], acc.z);
    atomicAdd(&ctx_acc[4 * t + 3], acc.w);
}

// ---------------- Kernel D/E: gates[r] = dot(Wih[r],x) + dot(Whh[r],hprev) + bih[r] + bhh[r] ----------------
// one wave per row; 1024 blocks x 256 threads = 4096 waves
// if ids != nullptr, x = emb + ids[0]*H, else x = xin
__global__ __launch_bounds__(256) void gates_kernel(
    const float* __restrict__ Wih, const float* __restrict__ Whh,
    const float* __restrict__ bih, const float* __restrict__ bhh,
    const float* __restrict__ xin, const float* __restrict__ emb,
    const int* __restrict__ ids,
    const float* __restrict__ hprev, float* __restrict__ gates) {
    int wave = (blockIdx.x * blockDim.x + threadIdx.x) >> 6;
    int lane = threadIdx.x & 63;
    const float* x = (ids != nullptr) ? (emb + (size_t)ids[0] * HH) : xin;
    const float4* A  = (const float4*)(Wih + (size_t)wave * HH);
    const float4* B  = (const float4*)(Whh + (size_t)wave * HH);
    const float4* xv = (const float4*)x;
    const float4* hv = (const float4*)hprev;
    float acc = 0.f;
    #pragma unroll
    for (int k = 0; k < 4; ++k) {
        float4 a  = A[lane + 64 * k];
        float4 xx = xv[lane + 64 * k];
        acc += a.x * xx.x + a.y * xx.y + a.z * xx.z + a.w * xx.w;
        float4 b  = B[lane + 64 * k];
        float4 hh = hv[lane + 64 * k];
        acc += b.x * hh.x + b.y * hh.y + b.z * hh.z + b.w * hh.w;
    }
    acc = wave_sum64(acc);
    if (lane == 0) gates[wave] = acc + bih[wave] + bhh[wave];
}

// ---------------- LSTM elementwise ----------------
// 4 blocks x 256 threads = 1024
__global__ __launch_bounds__(256) void lstm_elem_kernel(
    const float* __restrict__ gates, const float* __restrict__ c_prev,
    float* __restrict__ h_ws, float* __restrict__ c_ws,
    float* __restrict__ h_out, float* __restrict__ c_out) {
    int j = blockIdx.x * blockDim.x + threadIdx.x;
    float gi = gates[j];
    float gf = gates[j + 1024];
    float gg = gates[j + 2048];
    float go = gates[j + 3072];
    gi = 1.f / (1.f + expf(-gi));
    gf = 1.f / (1.f + expf(-gf));
    go = 1.f / (1.f + expf(-go));
    gg = tanhf(gg);
    float c = gf * c_prev[j] + gi * gg;
    float h = go * tanhf(c);
    h_ws[j] = h; c_ws[j] = c;
    h_out[j] = h; c_out[j] = c;
}

// ---------------- Kernel G: logits[r] = dot(W_out[r,:], h1) + b_out[r] ----------------
// one wave per row; 8000 blocks x 256 threads = 32000 waves
__global__ __launch_bounds__(256) void logits_kernel(
    const float* __restrict__ W, const float* __restrict__ b,
    const float* __restrict__ h, float* __restrict__ out) {
    int wave = (blockIdx.x * blockDim.x + threadIdx.x) >> 6;
    int lane = threadIdx.x & 63;
    const float4* Wr = (const float4*)(W + (size_t)wave * HH);
    const float4* hv = (const float4*)h;
    float acc = 0.f;
    #pragma unroll
    for (int k = 0; k < 4; ++k) {
        float4 w = Wr[lane + 64 * k];
        float4 x = hv[lane + 64 * k];
        acc += w.x * x.x + w.y * x.y + w.z * x.z + w.w * x.w;
    }
    acc = wave_sum64(acc);
    if (lane == 0) out[wave] = acc + b[wave];
}

extern "C" void kernel_launch(void* const* d_in, const int* in_sizes, int n_in,
                              void* d_out, int out_size, void* d_ws, size_t ws_size,
                              hipStream_t stream) {
    const int*   ids   = (const int*)  d_in[0];
    const float* h_in  = (const float*)d_in[1];   // (2,1,H): h[0,0] at offset 0
    const float* c_in  = (const float*)d_in[2];   // (2,1,H): c0 at 0, c1 at H
    const float* E     = (const float*)d_in[3];   // (S,H)
    const float* emb   = (const float*)d_in[4];   // (V,H)
    const float* Wih0  = (const float*)d_in[5];
    const float* Whh0  = (const float*)d_in[6];
    const float* bih0  = (const float*)d_in[7];
    const float* bhh0  = (const float*)d_in[8];
    const float* Wih1  = (const float*)d_in[9];
    const float* Whh1  = (const float*)d_in[10];
    const float* bih1  = (const float*)d_in[11];
    const float* bhh1  = (const float*)d_in[12];
    const float* Wout  = (const float*)d_in[13];
    const float* bout  = (const float*)d_in[14];

    float* out = (float*)d_out;
    float* logits   = out;                 // 32000
    float* h0_out   = out + 32000;         // h_new[0]
    float* h1_out   = out + 32000 + 1024;  // h_new[1]
    float* c0_out   = out + 34048;         // c_new[0]
    float* c1_out   = out + 34048 + 1024;  // c_new[1]
    float* attn_out = out + 36096;         // attn_w (2048)

    float* ws = (float*)d_ws;
    float* scores  = ws;            // 2048
    float* attn_ws = ws + 2048;     // 2048
    float* ctx     = ws + 4096;     // 1024
    float* gates0  = ws + 5120;     // 4096
    float* gates1  = ws + 9216;     // 4096
    float* h0_ws   = ws + 13312;    // 1024
    float* c0_ws   = ws + 14336;    // 1024
    float* h1_ws   = ws + 15360;    // 1024
    float* c1_ws   = ws + 16384;    // 1024

    // A: attention scores (2048 rows, one wave each)
    scores_kernel<<<512, 256, 0, stream>>>(E, h_in, scores);
    // B: softmax + write attn output + zero ctx accumulator
    softmax_kernel<<<1, 1024, 0, stream>>>(scores, attn_ws, attn_out, ctx);
    // C: ctx = attn @ E
    ctx_kernel<<<128, 256, 0, stream>>>(E, attn_ws, ctx);
    // D: LSTM0 gates (x = embedding[ids[0]], hprev = ctx)
    gates_kernel<<<1024, 256, 0, stream>>>(Wih0, Whh0, bih0, bhh0,
                                           nullptr, emb, ids, ctx, gates0);
    lstm_elem_kernel<<<4, 256, 0, stream>>>(gates0, c_in, h0_ws, c0_ws, h0_out, c0_out);
    // E: LSTM1 gates (x = h0, hprev = ctx)
    gates_kernel<<<1024, 256, 0, stream>>>(Wih1, Whh1, bih1, bhh1,
                                           h0_ws, nullptr, nullptr, ctx, gates1);
    lstm_elem_kernel<<<4, 256, 0, stream>>>(gates1, c_in + 1024, h1_ws, c1_ws, h1_out, c1_out);
    // G: logits = W_out @ h1 + b_out
    logits_kernel<<<8000, 256, 0, stream>>>(Wout, bout, h1_ws, logits);
}